// Round 1
// baseline (857.737 us; speedup 1.0000x reference)
//
#include <hip/hip_runtime.h>
#include <math.h>

// Problem constants (fixed by the reference):
//   B = 524288 rows, V = 128, x-width = 3*V = 384, R = 4, NC = 2.
#define ROWS   256   // rows per block (= block threads; 1 thread : 1 row)
#define V      128
#define NW     384   // N_VECS * V
#define CHUNK  32    // columns staged per LDS chunk
#define PAD    36    // LDS row stride in floats: 36 mod 32 = 4 -> conflict-free b128 phases

__device__ __forceinline__ float sigmoidf_(float x) {
    return 1.0f / (1.0f + expf(-x));
}

__global__ __launch_bounds__(256, 4)
void fused_ns_kernel(const float* __restrict__ ga,
                     const float* __restrict__ gb,
                     const float* __restrict__ gc,
                     const float* __restrict__ Wff,
                     const float* __restrict__ Wgd,
                     const float* __restrict__ W1,
                     const float* __restrict__ b1,
                     const float* __restrict__ W2,
                     const float* __restrict__ b2,
                     float* __restrict__ out)
{
    __shared__ float lds[ROWS * PAD];
    const int t = threadIdx.x;
    const long row0 = (long)blockIdx.x * ROWS;

    float accf[8] = {0,0,0,0,0,0,0,0};
    float accg[8] = {0,0,0,0,0,0,0,0};

    // Stream x = [a | b | c] in 12 chunks of 32 columns.
    for (int s = 0; s < 3; ++s) {
        const float* arr = (s == 0) ? ga : ((s == 1) ? gb : gc);
        for (int cc = 0; cc < 4; ++cc) {
            const int colbase = cc * CHUNK;      // column within this array
            const int wcol    = s * V + colbase; // column within the 384-wide x

            __syncthreads();  // protect LDS from previous chunk's readers
            // Coalesced stage: 256 rows x 32 floats = 2048 float4, 8 per thread.
            // For fixed k, a wave's 64 lanes cover 8 rows x 128B contiguous.
            #pragma unroll
            for (int k = 0; k < 8; ++k) {
                const int f  = t + (k << 8);   // flat float4 index in chunk
                const int r  = f >> 3;         // row within block tile
                const int c4 = f & 7;          // float4 within row-chunk
                float4 v = ((const float4*)(arr + (row0 + r) * V + colbase))[c4];
                *((float4*)(&lds[r * PAD + (c4 << 2)])) = v;
            }
            __syncthreads();

            // Compute: thread t consumes row t of the staged chunk.
            // W indices are wave-uniform (loop constants only) -> s_load path.
            const float* xr = &lds[t * PAD];
            #pragma unroll
            for (int jj = 0; jj < CHUNK; jj += 4) {
                const float4 xv = *((const float4*)(xr + jj));
                #pragma unroll
                for (int k = 0; k < 8; ++k) {
                    const float* wf = Wff + k * NW + wcol + jj;
                    accf[k] = fmaf(xv.x, wf[0],
                               fmaf(xv.y, wf[1],
                                fmaf(xv.z, wf[2],
                                 fmaf(xv.w, wf[3], accf[k]))));
                    const float* wg = Wgd + k * NW + wcol + jj;
                    accg[k] = fmaf(xv.x, wg[0],
                               fmaf(xv.y, wg[1],
                                fmaf(xv.z, wg[2],
                                 fmaf(xv.w, wg[3], accg[k]))));
                }
            }
        }
    }

    // Tail math (per row, ~100 FLOPs): sigmoid gate, 4x4 outer, W1, W2.
    float outs[8];
    #pragma unroll
    for (int k = 0; k < 8; ++k)
        outs[k] = sigmoidf_(accf[k]) * sigmoidf_(accg[k]);

    float h[4];
    #pragma unroll
    for (int r = 0; r < 4; ++r) {
        float acc = b1[r];
        #pragma unroll
        for (int aa = 0; aa < 4; ++aa)
            #pragma unroll
            for (int bb = 0; bb < 4; ++bb)
                acc = fmaf(outs[aa] * outs[4 + bb], W1[r * 16 + aa * 4 + bb], acc);
        h[r] = fmaxf(acc, 0.0f);
    }

    float p[2];
    #pragma unroll
    for (int cc2 = 0; cc2 < 2; ++cc2) {
        float acc = b2[cc2];
        #pragma unroll
        for (int r = 0; r < 4; ++r)
            acc = fmaf(h[r], W2[cc2 * 4 + r], acc);
        p[cc2] = sigmoidf_(acc);
    }

    out[row0 + t] = (p[0] - p[1] + 1.0f) * 0.5f;
}

extern "C" void kernel_launch(void* const* d_in, const int* in_sizes, int n_in,
                              void* d_out, int out_size, void* d_ws, size_t ws_size,
                              hipStream_t stream) {
    const float* a   = (const float*)d_in[0];
    const float* b   = (const float*)d_in[1];
    const float* c   = (const float*)d_in[2];
    const float* Wff = (const float*)d_in[3];
    const float* Wgd = (const float*)d_in[4];
    const float* W1  = (const float*)d_in[5];
    const float* b1  = (const float*)d_in[6];
    const float* W2  = (const float*)d_in[7];
    const float* b2  = (const float*)d_in[8];
    float* out = (float*)d_out;

    const int nrows = in_sizes[0] / V;   // 524288
    const int grid  = nrows / ROWS;      // 2048, no tail (524288 % 256 == 0)

    fused_ns_kernel<<<grid, ROWS, 0, stream>>>(a, b, c, Wff, Wgd, W1, b1, W2, b2, out);
}

// Round 2
// 716.347 us; speedup vs baseline: 1.1974x; 1.1974x over previous
//
#include <hip/hip_runtime.h>
#include <math.h>

// B = 524288 rows, x-width = 384 (3 arrays of V=128), 16 outputs (8 f + 8 g).
// Skinny GEMM via mfma_f32_16x16x32_bf16 with 3-pass bf16 split for f32 accuracy.
typedef __attribute__((ext_vector_type(8))) short bf16x8;
typedef __attribute__((ext_vector_type(4))) float f32x4;

#define V   128
#define NW  384
#define TILES_PER_WAVE  8
#define WAVES_PER_BLOCK 4
// grid = 1024 blocks * 4 waves * 8 tiles * 16 rows = 524288 rows exactly.

__device__ __forceinline__ float sigmoidf_(float x) { return 1.0f / (1.0f + expf(-x)); }

// Split 8 f32 into hi/lo bf16 fragments (truncation; lo captures next 8 bits).
__device__ __forceinline__ void split8(float4 u0, float4 u1, bf16x8& h, bf16x8& l) {
    float uu[8] = {u0.x, u0.y, u0.z, u0.w, u1.x, u1.y, u1.z, u1.w};
    #pragma unroll
    for (int j = 0; j < 8; ++j) {
        unsigned b  = __float_as_uint(uu[j]);
        unsigned hb = b & 0xFFFF0000u;
        float r = uu[j] - __uint_as_float(hb);   // exact (aligned subtract)
        h[j] = (short)(b >> 16);
        l[j] = (short)(__float_as_uint(r) >> 16);
    }
}

__global__ __launch_bounds__(256)
void fused_ns_mfma(const float* __restrict__ ga, const float* __restrict__ gb,
                   const float* __restrict__ gc, const float* __restrict__ Wff,
                   const float* __restrict__ Wgd, const float* __restrict__ W1,
                   const float* __restrict__ b1,  const float* __restrict__ W2,
                   const float* __restrict__ b2,  float* __restrict__ out)
{
    // Per-wave private transpose buffer; [16][20] pad -> worst 2-way conflicts (free).
    __shared__ float lds[WAVES_PER_BLOCK][16][20];
    const int t  = threadIdx.x & 63;
    const int w  = threadIdx.x >> 6;
    const int gw = blockIdx.x * WAVES_PER_BLOCK + w;   // 0..4095
    const int lr = t & 15;    // A-row / B-col / C-col
    const int kb = t >> 4;    // k-block: lane holds k = kb*8 + j

    // ---- Persistent weight fragments: W = [Wff(8 rows); Wgd(8 rows)], row-major [16][384].
    // B-frag lane l: col = l&15, 8 consecutive k at kc*32 + kb*8 (contiguous in the W row).
    const float* wrow = (lr < 8) ? (Wff + lr * NW) : (Wgd + (lr - 8) * NW);
    bf16x8 wh[12], wl[12];
    #pragma unroll
    for (int kc = 0; kc < 12; ++kc) {
        const float* p = wrow + kc * 32 + kb * 8;
        float4 u0 = *(const float4*)(p);
        float4 u1 = *(const float4*)(p + 4);
        split8(u0, u1, wh[kc], wl[kc]);
    }

    float* buf = &lds[w][0][0];

    #pragma unroll 1   // keep VGPRs bounded; compiler still pipelines within a tile
    for (int i = 0; i < TILES_PER_WAVE; ++i) {
        const long row0 = ((long)gw * TILES_PER_WAVE + i) * 16;
        const float* xa = ga + (row0 + lr) * V + kb * 8;
        const float* xb = gb + (row0 + lr) * V + kb * 8;
        const float* xc = gc + (row0 + lr) * V + kb * 8;

        f32x4 acc = {0.f, 0.f, 0.f, 0.f};
        #pragma unroll
        for (int s = 0; s < 3; ++s) {
            const float* xr = (s == 0) ? xa : ((s == 1) ? xb : xc);
            #pragma unroll
            for (int cc = 0; cc < 4; ++cc) {
                // A-frag: wave's two dwordx4 cover 16 rows x 128B fully coalesced.
                float4 u0 = *(const float4*)(xr + cc * 32);
                float4 u1 = *(const float4*)(xr + cc * 32 + 4);
                bf16x8 xh, xl;
                split8(u0, u1, xh, xl);
                const int kc = s * 4 + cc;
                acc = __builtin_amdgcn_mfma_f32_16x16x32_bf16(xh, wh[kc], acc, 0, 0, 0);
                acc = __builtin_amdgcn_mfma_f32_16x16x32_bf16(xh, wl[kc], acc, 0, 0, 0);
                acc = __builtin_amdgcn_mfma_f32_16x16x32_bf16(xl, wh[kc], acc, 0, 0, 0);
            }
        }

        // C/D layout (m89-verified): col = lane&15, row = (lane>>4)*4 + r.
        #pragma unroll
        for (int r = 0; r < 4; ++r)
            buf[(kb * 4 + r) * 20 + lr] = acc[r];
        // Per-wave buffer: compiler inserts lgkmcnt ordering; no barrier needed.

        if (t < 16) {   // one lane per row does the ~100-FLOP tail
            const float* rp = buf + t * 20;
            float o8[8];
            #pragma unroll
            for (int j = 0; j < 8; ++j)
                o8[j] = sigmoidf_(rp[j]) * sigmoidf_(rp[8 + j]);
            float hh[4];
            #pragma unroll
            for (int r = 0; r < 4; ++r) {
                float a1 = b1[r];
                #pragma unroll
                for (int aa = 0; aa < 4; ++aa)
                    #pragma unroll
                    for (int bb = 0; bb < 4; ++bb)
                        a1 = fmaf(o8[aa] * o8[4 + bb], W1[r * 16 + aa * 4 + bb], a1);
                hh[r] = fmaxf(a1, 0.f);
            }
            float p0 = b2[0], p1 = b2[1];
            #pragma unroll
            for (int r = 0; r < 4; ++r) {
                p0 = fmaf(hh[r], W2[r], p0);
                p1 = fmaf(hh[r], W2[4 + r], p1);
            }
            out[row0 + t] = (sigmoidf_(p0) - sigmoidf_(p1) + 1.f) * 0.5f;
        }
    }
}

extern "C" void kernel_launch(void* const* d_in, const int* in_sizes, int n_in,
                              void* d_out, int out_size, void* d_ws, size_t ws_size,
                              hipStream_t stream) {
    const float* a   = (const float*)d_in[0];
    const float* b   = (const float*)d_in[1];
    const float* c   = (const float*)d_in[2];
    const float* Wff = (const float*)d_in[3];
    const float* Wgd = (const float*)d_in[4];
    const float* W1  = (const float*)d_in[5];
    const float* b1  = (const float*)d_in[6];
    const float* W2  = (const float*)d_in[7];
    const float* b2  = (const float*)d_in[8];
    float* out = (float*)d_out;

    const int grid = 1024;   // 1024 blocks x 4 waves x 8 tiles x 16 rows = 524288
    fused_ns_mfma<<<grid, 64 * WAVES_PER_BLOCK, 0, stream>>>(
        a, b, c, Wff, Wgd, W1, b1, W2, b2, out);
}